// Round 4
// baseline (265.907 us; speedup 1.0000x reference)
//
#include <hip/hip_runtime.h>
#include <hip/hip_bf16.h>

// B=4, L=128, C=1024, D=512, fp32.
// out[b,l,c] = softmax_c( sum_d V[d]*tanh(wq[b,l,d] + uc[b,c,d]) )
// tanh(x) = 1 - 2/(e^{2x}+1);  e^{2(wq+uc)} = e^{2wq} * e^{2uc};
// softmax shift-invariance drops the constant sum(V):
//   align'[b,l,c] = sum_d (-2 V_d) * rcp(ewq[b,d,l]*euc[b,d,c] + 1)
//
// R4:
//  gemm_v5: m-tile 8 (weights via s_load, 32 SGPR/kb -> double-bufferable),
//           X staged in LDS (Xs[2][64][66], float2 reads, conflict-free),
//           4608 waves. VALU-bound by construction.
//  fused_align4: align2 structure, but wq via s_load_dwordx4 (scalar pipe)
//           instead of LDS broadcast; uc via per-lane ds_read_b32 (2-way free).

#define SCALE2 2.8853900817779268f  // 2*log2(e)

// ---------------------------------------------------------------------------
// 64x64 transpose of the two 512x512 weight matrices. blockIdx.z: 0=W, 1=U.
// ---------------------------------------------------------------------------
__global__ __launch_bounds__(256) void transpose512(
    const float* __restrict__ W, const float* __restrict__ U,
    float* __restrict__ Wt, float* __restrict__ Ut)
{
    __shared__ float t[64][65];
    const float* src = blockIdx.z ? U : W;
    float* dst = blockIdx.z ? Ut : Wt;
    const int bx = blockIdx.x * 64;
    const int by = blockIdx.y * 64;
    const int r  = threadIdx.x >> 2;
    const int c4 = (threadIdx.x & 3) * 16;
#pragma unroll
    for (int p = 0; p < 4; ++p) {
        float4 v = *(const float4*)(src + (size_t)(by + r) * 512 + bx + c4 + p * 4);
        t[r][c4 + p * 4 + 0] = v.x;
        t[r][c4 + p * 4 + 1] = v.y;
        t[r][c4 + p * 4 + 2] = v.z;
        t[r][c4 + p * 4 + 3] = v.w;
    }
    __syncthreads();
#pragma unroll
    for (int p = 0; p < 4; ++p) {
        float4 o;
        o.x = t[c4 + p * 4 + 0][r];
        o.y = t[c4 + p * 4 + 1][r];
        o.z = t[c4 + p * 4 + 2][r];
        o.w = t[c4 + p * 4 + 3][r];
        *(float4*)(dst + (size_t)(bx + r) * 512 + by + c4 + p * 4) = o;
    }
}

// ---------------------------------------------------------------------------
// GEMM + exp2, transposed output. Block = 4 waves; wave owns 8 m-rows x 64
// cols; block = 32 m-rows. X (the n-side rows) staged in LDS per 64-k chunk.
// Weights read wave-uniform from transposed At[k][m] -> s_load (scalar pipe).
// blocks 0..127: wq (X=hidden); 128..1151: uc (X=ctx). db is the fast block
// dim so blocks sharing an X strip dispatch together (L2 temporal locality).
// ---------------------------------------------------------------------------
__global__ __launch_bounds__(256) void gemm_v5(
    const float* __restrict__ hidden, const float* __restrict__ ctx,
    const float* __restrict__ Wt, const float* __restrict__ Ut,
    const float* __restrict__ U_b,
    float* __restrict__ ewq_t, float* __restrict__ euc_t)
{
    __shared__ float Xs[2][64][66];

    const int tid  = threadIdx.x;
    const int w    = __builtin_amdgcn_readfirstlane(tid >> 6);
    const int lane = tid & 63;

    const float *At, *X, *bias;
    float* Cb;
    int m0;
    size_t ostride;
    {
        int gb = blockIdx.x;
        if (gb < 128) {
            const int db = gb & 15, nt = gb >> 4;     // nt in [0,8)
            m0 = db * 32 + w * 8;
            const int ncol0 = nt * 64;                // [0,512)
            const int b = ncol0 >> 7, l0 = ncol0 & 127;
            At = Wt; bias = nullptr;
            X  = hidden + (size_t)ncol0 * 512;
            Cb = ewq_t + ((size_t)b * 512 + m0) * 128 + l0;
            ostride = 128;
        } else {
            const int gg = gb - 128;
            const int db = gg & 15, nt = gg >> 4;     // nt in [0,64)
            m0 = db * 32 + w * 8;
            const int ncol0 = nt * 64;                // [0,4096)
            const int b = ncol0 >> 10, c0 = ncol0 & 1023;
            At = Ut; bias = U_b;
            X  = ctx + (size_t)ncol0 * 512;
            Cb = euc_t + ((size_t)b * 512 + m0) * 1024 + c0;
            ostride = 1024;
        }
    }

    // staging map: thread -> (row, 16-k slice)
    const int srow = tid & 63;
    const int skq  = (tid >> 6) * 16;
    const float* xsrc = X + (size_t)srow * 512 + skq;

    float acc[8];
#pragma unroll
    for (int j = 0; j < 8; ++j) acc[j] = 0.0f;

    // prologue: stage kc=0
    {
#pragma unroll
        for (int i = 0; i < 4; ++i) {
            float4 v = *(const float4*)(xsrc + i * 4);
            *(float2*)&Xs[0][srow][skq + i * 4]     = make_float2(v.x, v.y);
            *(float2*)&Xs[0][srow][skq + i * 4 + 2] = make_float2(v.z, v.w);
        }
    }
    __syncthreads();

    int buf = 0;
    for (int kc = 0; kc < 8; ++kc) {
        float4 nx[4];
        if (kc < 7) {
#pragma unroll
            for (int i = 0; i < 4; ++i)
                nx[i] = *(const float4*)(xsrc + (kc + 1) * 64 + i * 4);
        }
        const float* wk = At + (size_t)(kc * 64) * 512 + m0;
#pragma unroll
        for (int kb = 0; kb < 16; ++kb) {
            const float2 x01 = *(const float2*)&Xs[buf][lane][kb * 4];
            const float2 x23 = *(const float2*)&Xs[buf][lane][kb * 4 + 2];
            const float* wr = wk + (size_t)kb * 2048;
#pragma unroll
            for (int j = 0; j < 8; ++j) acc[j] = fmaf(wr[j], x01.x, acc[j]);
#pragma unroll
            for (int j = 0; j < 8; ++j) acc[j] = fmaf(wr[512 + j], x01.y, acc[j]);
#pragma unroll
            for (int j = 0; j < 8; ++j) acc[j] = fmaf(wr[1024 + j], x23.x, acc[j]);
#pragma unroll
            for (int j = 0; j < 8; ++j) acc[j] = fmaf(wr[1536 + j], x23.y, acc[j]);
        }
        if (kc < 7) {
#pragma unroll
            for (int i = 0; i < 4; ++i) {
                *(float2*)&Xs[buf ^ 1][srow][skq + i * 4]     = make_float2(nx[i].x, nx[i].y);
                *(float2*)&Xs[buf ^ 1][srow][skq + i * 4 + 2] = make_float2(nx[i].z, nx[i].w);
            }
            __syncthreads();
            buf ^= 1;
        }
    }

#pragma unroll
    for (int j = 0; j < 8; ++j) {
        const float bl = bias ? bias[m0 + j] : 0.0f;
        Cb[(size_t)j * ostride + lane] =
            __builtin_amdgcn_exp2f(SCALE2 * (acc[j] + bl));
    }
}

// ---------------------------------------------------------------------------
// Fused align: block = (64 c's, 16 l's, b); 4 waves, wave w owns l0..l0+3.
// uc tile staged in LDS (per-lane b32 reads, 2-way free); wq + V read
// wave-uniform -> scalar loads (s_load_dwordx4 / s_load) on the SMEM pipe.
// ---------------------------------------------------------------------------
__global__ __launch_bounds__(256) void fused_align4(
    const float* __restrict__ ewq_t,  // [4][512][128]
    const float* __restrict__ euc_t,  // [4][512][1024]
    const float* __restrict__ Vv,     // [512]
    float* __restrict__ out)          // [4][128][1024]
{
    __shared__ float uc_s[128][64];   // 32 KB
    const int tid  = threadIdx.x;
    const int lane = tid & 63;
    const int w    = __builtin_amdgcn_readfirstlane(tid >> 6);
    const int c0   = blockIdx.x * 64;   // 16
    const int lblk = blockIdx.y * 16;   // 8
    const int b    = blockIdx.z;        // 4

    const float* ucb = euc_t + (size_t)b * 512 * 1024 + c0;
    const float* wqb = ewq_t + (size_t)b * 512 * 128 + lblk + w * 4;

    float a0 = 0.f, a1 = 0.f, a2 = 0.f, a3 = 0.f;

    for (int dc = 0; dc < 4; ++dc) {
        __syncthreads();
        {   // stage euc tile [128 d][64 c]
            const float* src = ucb + (size_t)(dc * 128) * 1024;
            const int row = tid >> 4, col = (tid & 15) * 4;
#pragma unroll
            for (int p = 0; p < 8; ++p)
                *(float4*)&uc_s[p * 16 + row][col] =
                    *(const float4*)(src + (size_t)(p * 16 + row) * 1024 + col);
        }
        __syncthreads();

        const float* qp = wqb + (size_t)(dc * 128) * 128;
        const float* vp = Vv + dc * 128;
#pragma unroll 8
        for (int d = 0; d < 128; ++d) {
            const float  e = uc_s[d][lane];
            const float4 q = *(const float4*)(qp + (size_t)d * 128);
            const float  v = vp[d];
            a0 = fmaf(v, __builtin_amdgcn_rcpf(fmaf(q.x, e, 1.0f)), a0);
            a1 = fmaf(v, __builtin_amdgcn_rcpf(fmaf(q.y, e, 1.0f)), a1);
            a2 = fmaf(v, __builtin_amdgcn_rcpf(fmaf(q.z, e, 1.0f)), a2);
            a3 = fmaf(v, __builtin_amdgcn_rcpf(fmaf(q.w, e, 1.0f)), a3);
        }
    }

    float* op = out + ((size_t)b * 128 + lblk + w * 4) * 1024 + c0 + lane;
    op[0]    = -2.0f * a0;
    op[1024] = -2.0f * a1;
    op[2048] = -2.0f * a2;
    op[3072] = -2.0f * a3;
}

// in-place softmax over rows of 1024; one wave per row
__global__ __launch_bounds__(256) void softmax_kernel(float* __restrict__ data)
{
    const int row  = blockIdx.x * 4 + (threadIdx.x >> 6);
    const int lane = threadIdx.x & 63;
    float* p = data + (size_t)row * 1024;

    float4 x[4];
#pragma unroll
    for (int j = 0; j < 4; ++j) x[j] = *(const float4*)(p + j * 256 + lane * 4);

    float m = x[0].x;
#pragma unroll
    for (int j = 0; j < 4; ++j) {
        m = fmaxf(m, x[j].x); m = fmaxf(m, x[j].y);
        m = fmaxf(m, x[j].z); m = fmaxf(m, x[j].w);
    }
#pragma unroll
    for (int mask = 32; mask >= 1; mask >>= 1) m = fmaxf(m, __shfl_xor(m, mask, 64));

    const float LOG2E = 1.4426950408889634f;
    float s = 0.0f;
#pragma unroll
    for (int j = 0; j < 4; ++j) {
        x[j].x = __builtin_amdgcn_exp2f((x[j].x - m) * LOG2E);
        x[j].y = __builtin_amdgcn_exp2f((x[j].y - m) * LOG2E);
        x[j].z = __builtin_amdgcn_exp2f((x[j].z - m) * LOG2E);
        x[j].w = __builtin_amdgcn_exp2f((x[j].w - m) * LOG2E);
        s += x[j].x + x[j].y + x[j].z + x[j].w;
    }
#pragma unroll
    for (int mask = 32; mask >= 1; mask >>= 1) s += __shfl_xor(s, mask, 64);
    const float r = __builtin_amdgcn_rcpf(s);
#pragma unroll
    for (int j = 0; j < 4; ++j) {
        x[j].x *= r; x[j].y *= r; x[j].z *= r; x[j].w *= r;
        *(float4*)(p + j * 256 + lane * 4) = x[j];
    }
}

extern "C" void kernel_launch(void* const* d_in, const int* in_sizes, int n_in,
                              void* d_out, int out_size, void* d_ws, size_t ws_size,
                              hipStream_t stream)
{
    const float* hidden = (const float*)d_in[0];  // [4,128,512]
    const float* ctx    = (const float*)d_in[1];  // [4,1024,512]
    const float* W      = (const float*)d_in[2];  // [512,512]
    const float* U      = (const float*)d_in[3];  // [512,512]
    const float* U_b    = (const float*)d_in[4];  // [512]
    const float* V      = (const float*)d_in[5];  // [512]
    float* out = (float*)d_out;                   // [4,128,1024]

    float* ewq_t = (float*)d_ws;                  // [4][512][128]  (1 MB)
    float* euc_t = ewq_t + 4 * 512 * 128;         // [4][512][1024] (8 MB)
    float* Wt    = euc_t + 4 * 512 * 1024;        // [512][512]     (1 MB)
    float* Ut    = Wt + 512 * 512;                // [512][512]     (1 MB)

    transpose512<<<dim3(8, 8, 2), 256, 0, stream>>>(W, U, Wt, Ut);
    gemm_v5<<<1152, 256, 0, stream>>>(hidden, ctx, Wt, Ut, U_b, ewq_t, euc_t);
    fused_align4<<<dim3(16, 8, 4), 256, 0, stream>>>(ewq_t, euc_t, V, out);
    softmax_kernel<<<128, 256, 0, stream>>>(out);
}

// Round 5
// 153.333 us; speedup vs baseline: 1.7342x; 1.7342x over previous
//
#include <hip/hip_runtime.h>
#include <hip/hip_bf16.h>

// B=4, L=128, C=1024, D=512, fp32.
// out[b,l,c] = softmax_c( sum_d V[d]*tanh(wq[b,l,d] + uc[b,c,d]) )
// tanh(x) = 1 - 2/(e^{2x}+1);  e^{2(wq+uc)} = e^{2wq} * e^{2uc};
// softmax shift-invariance drops the constant sum(V):
//   align'[b,l,c] = sum_d (-2 V_d) * rcp(ewq[b,d,l]*euc[b,d,c] + 1)
//
// R5 design rules learned so far:
//  - NO scalar (s_load) operands in hot loops: SMEM shares lgkmcnt with LDS
//    and returns out-of-order -> lgkmcnt(0) serialization (R4 disaster).
//  - LDS b128 is 85 B/cyc/CU shared by 4 SIMDs: feed only ONE GEMM operand
//    from LDS; weights come from global (L1: 8KB/chunk working set).
//  - gemm6: tile 64c x 128m, 256 thr, micro 4c x 8m. Per wave per k:
//    1 ds_read_b128 (2-way, free) + 2 global b128 + 32 fma -> VALU-bound.
//    1152 waves. fp32 VALU floor ~30us.
//  - align5: 2 c/lane via two b32 reads (halves split +68 to stay 2-way
//    free), 4 l/wave via one uniform b128; LDS ~= VALU ~= 20.5us floor.

#define SCALE2 2.8853900817779268f  // 2*log2(e)

// ---------------------------------------------------------------------------
// 64x64 transpose of the two 512x512 weight matrices. blockIdx.z: 0=W, 1=U.
// ---------------------------------------------------------------------------
__global__ __launch_bounds__(256) void transpose512(
    const float* __restrict__ W, const float* __restrict__ U,
    float* __restrict__ Wt, float* __restrict__ Ut)
{
    __shared__ float t[64][65];
    const float* src = blockIdx.z ? U : W;
    float* dst = blockIdx.z ? Ut : Wt;
    const int bx = blockIdx.x * 64;
    const int by = blockIdx.y * 64;
    const int r  = threadIdx.x >> 2;
    const int c4 = (threadIdx.x & 3) * 16;
#pragma unroll
    for (int p = 0; p < 4; ++p) {
        float4 v = *(const float4*)(src + (size_t)(by + r) * 512 + bx + c4 + p * 4);
        t[r][c4 + p * 4 + 0] = v.x;
        t[r][c4 + p * 4 + 1] = v.y;
        t[r][c4 + p * 4 + 2] = v.z;
        t[r][c4 + p * 4 + 3] = v.w;
    }
    __syncthreads();
#pragma unroll
    for (int p = 0; p < 4; ++p) {
        float4 o;
        o.x = t[c4 + p * 4 + 0][r];
        o.y = t[c4 + p * 4 + 1][r];
        o.z = t[c4 + p * 4 + 2][r];
        o.w = t[c4 + p * 4 + 3][r];
        *(float4*)(dst + (size_t)(bx + r) * 512 + by + c4 + p * 4) = o;
    }
}

// ---------------------------------------------------------------------------
// GEMM + exp2 + transposed store.  C_t[b][m][c] = exp2(S2*(X[c]·At[:,m]+bias))
// Tile: 64 c x 128 m, 256 threads, micro 4c x 8m.
// X tile in LDS (double-buffered, 16-k chunks); weights At[k][m] streamed
// from global per-lane b128 (L1-resident: 8KB per chunk).
// blocks 0..31: wq (X=hidden, 512 rows); 32..287: uc (X=ctx, 4096 rows).
// ---------------------------------------------------------------------------
__global__ __launch_bounds__(256) void gemm6(
    const float* __restrict__ hidden, const float* __restrict__ ctx,
    const float* __restrict__ Wt, const float* __restrict__ Ut,
    const float* __restrict__ U_b,
    float* __restrict__ ewq_t, float* __restrict__ euc_t)
{
    __shared__ float As[2][16][64];

    const int tid = threadIdx.x;
    const int tc  = tid & 15;    // c micro (4 c's)
    const int tm  = tid >> 4;    // m micro (8 m's)

    const float *X, *At, *bias;
    float* Ct;
    int m0, ncol0, mbshift;
    {
        int gb = blockIdx.x;
        if (gb < 32) {
            ncol0 = (gb & 7) * 64;  m0 = (gb >> 3) * 128;
            X = hidden; At = Wt; bias = nullptr; Ct = ewq_t; mbshift = 7;
        } else {
            int g = gb - 32;
            ncol0 = (g & 63) * 64;  m0 = (g >> 6) * 128;
            X = ctx; At = Ut; bias = U_b; Ct = euc_t; mbshift = 10;
        }
    }

    // staging map: thread -> (c-row, k-quad)
    const int sr  = tid & 63;
    const int skq = (tid >> 6) * 4;
    const float* xsrc = X + (size_t)(ncol0 + sr) * 512 + skq;

    float acc[4][8];
#pragma unroll
    for (int i = 0; i < 4; ++i)
#pragma unroll
        for (int j = 0; j < 8; ++j) acc[i][j] = 0.0f;

    // prologue: stage chunk 0
    {
        float4 v = *(const float4*)xsrc;
        As[0][skq + 0][sr] = v.x; As[0][skq + 1][sr] = v.y;
        As[0][skq + 2][sr] = v.z; As[0][skq + 3][sr] = v.w;
    }
    __syncthreads();

    const float* wbase = At + m0 + tm * 8;

    for (int kc = 0; kc < 32; ++kc) {
        const int buf = kc & 1;
        float4 nv;
        if (kc < 31) nv = *(const float4*)(xsrc + (kc + 1) * 16);

        const float* wb = wbase + (size_t)(kc * 16) * 512;
#pragma unroll
        for (int k = 0; k < 16; ++k) {
            const float4 a  = *(const float4*)&As[buf][k][tc * 4];
            const float4 b0 = *(const float4*)(wb + (size_t)k * 512);
            const float4 b1 = *(const float4*)(wb + (size_t)k * 512 + 4);
            const float af[4] = {a.x, a.y, a.z, a.w};
            const float bf[8] = {b0.x, b0.y, b0.z, b0.w, b1.x, b1.y, b1.z, b1.w};
#pragma unroll
            for (int i = 0; i < 4; ++i)
#pragma unroll
                for (int j = 0; j < 8; ++j)
                    acc[i][j] = fmaf(af[i], bf[j], acc[i][j]);
        }

        if (kc < 31) {
            As[buf ^ 1][skq + 0][sr] = nv.x; As[buf ^ 1][skq + 1][sr] = nv.y;
            As[buf ^ 1][skq + 2][sr] = nv.z; As[buf ^ 1][skq + 3][sr] = nv.w;
            __syncthreads();
        }
    }

    // epilogue: bias + exp2 + transposed store
    float bl[8];
    if (bias) {
        float4 t0 = *(const float4*)&bias[m0 + tm * 8];
        float4 t1 = *(const float4*)&bias[m0 + tm * 8 + 4];
        bl[0] = t0.x; bl[1] = t0.y; bl[2] = t0.z; bl[3] = t0.w;
        bl[4] = t1.x; bl[5] = t1.y; bl[6] = t1.z; bl[7] = t1.w;
    } else {
#pragma unroll
        for (int j = 0; j < 8; ++j) bl[j] = 0.0f;
    }
    const int Mb  = 1 << mbshift;
    const int bb  = ncol0 >> mbshift;
    const int cl0 = (ncol0 & (Mb - 1)) + tc * 4;
    float* obase = Ct + ((size_t)bb * 512 + m0 + tm * 8) * Mb + cl0;
#pragma unroll
    for (int j = 0; j < 8; ++j) {
        float4 o;
        o.x = __builtin_amdgcn_exp2f(SCALE2 * (acc[0][j] + bl[j]));
        o.y = __builtin_amdgcn_exp2f(SCALE2 * (acc[1][j] + bl[j]));
        o.z = __builtin_amdgcn_exp2f(SCALE2 * (acc[2][j] + bl[j]));
        o.w = __builtin_amdgcn_exp2f(SCALE2 * (acc[3][j] + bl[j]));
        *(float4*)(obase + (size_t)j * Mb) = o;
    }
}

// ---------------------------------------------------------------------------
// Fused align: block = (128 c, 16 l, b); 4 waves; wave w owns l0..l0+3.
// Lane owns c0+lane and c0+64+lane (second half stored at col+68 so both
// reads are 2-way bank-free). q: one uniform ds_read_b128 per d.
// d in 16 chunks of 32, reg-double-buffered staging (T14 style).
// ---------------------------------------------------------------------------
__global__ __launch_bounds__(256) void fused_align5(
    const float* __restrict__ ewq_t,  // [4][512][128]
    const float* __restrict__ euc_t,  // [4][512][1024]
    const float* __restrict__ Vv,     // [512]
    float* __restrict__ out)          // [4][128][1024]
{
    __shared__ float uc_s[32][132];
    __shared__ float wq_s[32][16];

    const int tid  = threadIdx.x;
    const int lane = tid & 63;
    const int w    = __builtin_amdgcn_readfirstlane(tid >> 6);
    const int c0   = blockIdx.x * 128;  // 8
    const int lblk = blockIdx.y * 16;   // 8
    const int b    = blockIdx.z;        // 4

    // staging maps
    const int ud = tid >> 3;            // 0..31 d
    const int uq = tid & 7;             // col groups: 4*(uq + 8i)
    const float* ucb = euc_t + (size_t)b * 512 * 1024 + c0;
    const float* wqb = ewq_t + (size_t)b * 512 * 128 + lblk;
    const int wd = tid >> 2, wl = (tid & 3) * 4;   // tid<128 only

    float4 ur[4];
    float4 wr;
    {   // load chunk 0 into regs
        const float* src = ucb + (size_t)ud * 1024;
#pragma unroll
        for (int i = 0; i < 4; ++i)
            ur[i] = *(const float4*)(src + (uq + 8 * i) * 4);
        if (tid < 128)
            wr = *(const float4*)(wqb + (size_t)wd * 128 + wl);
    }

    float a00 = 0.f, a01 = 0.f, a10 = 0.f, a11 = 0.f;
    float a20 = 0.f, a21 = 0.f, a30 = 0.f, a31 = 0.f;

    for (int dc = 0; dc < 16; ++dc) {
        __syncthreads();   // previous compute done before overwrite
#pragma unroll
        for (int i = 0; i < 4; ++i) {
            const int c = (uq + 8 * i) * 4;                 // 0..124
            const int cs = c + ((c >> 6) << 2);             // +4 for c>=64
            *(float4*)&uc_s[ud][cs] = ur[i];
        }
        if (tid < 128) *(float4*)&wq_s[wd][wl] = wr;
        __syncthreads();

        if (dc < 15) {   // issue next-chunk loads; hide under compute
            const float* src = ucb + (size_t)((dc + 1) * 32 + ud) * 1024;
#pragma unroll
            for (int i = 0; i < 4; ++i)
                ur[i] = *(const float4*)(src + (uq + 8 * i) * 4);
            if (tid < 128)
                wr = *(const float4*)(wqb + (size_t)((dc + 1) * 32 + wd) * 128 + wl);
        }

        const float* vp = Vv + dc * 32;
#pragma unroll 8
        for (int d = 0; d < 32; ++d) {
            const float e0 = uc_s[d][lane];
            const float e1 = uc_s[d][lane + 68];
            const float4 q = *(const float4*)&wq_s[d][w * 4];
            const float vv = vp[d];
            a00 = fmaf(vv, __builtin_amdgcn_rcpf(fmaf(q.x, e0, 1.0f)), a00);
            a01 = fmaf(vv, __builtin_amdgcn_rcpf(fmaf(q.x, e1, 1.0f)), a01);
            a10 = fmaf(vv, __builtin_amdgcn_rcpf(fmaf(q.y, e0, 1.0f)), a10);
            a11 = fmaf(vv, __builtin_amdgcn_rcpf(fmaf(q.y, e1, 1.0f)), a11);
            a20 = fmaf(vv, __builtin_amdgcn_rcpf(fmaf(q.z, e0, 1.0f)), a20);
            a21 = fmaf(vv, __builtin_amdgcn_rcpf(fmaf(q.z, e1, 1.0f)), a21);
            a30 = fmaf(vv, __builtin_amdgcn_rcpf(fmaf(q.w, e0, 1.0f)), a30);
            a31 = fmaf(vv, __builtin_amdgcn_rcpf(fmaf(q.w, e1, 1.0f)), a31);
        }
    }

    float* op = out + ((size_t)b * 128 + lblk + w * 4) * 1024 + c0 + lane;
    op[0]         = -2.0f * a00;  op[64]        = -2.0f * a01;
    op[1024]      = -2.0f * a10;  op[1024 + 64] = -2.0f * a11;
    op[2048]      = -2.0f * a20;  op[2048 + 64] = -2.0f * a21;
    op[3072]      = -2.0f * a30;  op[3072 + 64] = -2.0f * a31;
}

// in-place softmax over rows of 1024; one wave per row
__global__ __launch_bounds__(256) void softmax_kernel(float* __restrict__ data)
{
    const int row  = blockIdx.x * 4 + (threadIdx.x >> 6);
    const int lane = threadIdx.x & 63;
    float* p = data + (size_t)row * 1024;

    float4 x[4];
#pragma unroll
    for (int j = 0; j < 4; ++j) x[j] = *(const float4*)(p + j * 256 + lane * 4);

    float m = x[0].x;
#pragma unroll
    for (int j = 0; j < 4; ++j) {
        m = fmaxf(m, x[j].x); m = fmaxf(m, x[j].y);
        m = fmaxf(m, x[j].z); m = fmaxf(m, x[j].w);
    }
#pragma unroll
    for (int mask = 32; mask >= 1; mask >>= 1) m = fmaxf(m, __shfl_xor(m, mask, 64));

    const float LOG2E = 1.4426950408889634f;
    float s = 0.0f;
#pragma unroll
    for (int j = 0; j < 4; ++j) {
        x[j].x = __builtin_amdgcn_exp2f((x[j].x - m) * LOG2E);
        x[j].y = __builtin_amdgcn_exp2f((x[j].y - m) * LOG2E);
        x[j].z = __builtin_amdgcn_exp2f((x[j].z - m) * LOG2E);
        x[j].w = __builtin_amdgcn_exp2f((x[j].w - m) * LOG2E);
        s += x[j].x + x[j].y + x[j].z + x[j].w;
    }
#pragma unroll
    for (int mask = 32; mask >= 1; mask >>= 1) s += __shfl_xor(s, mask, 64);
    const float r = __builtin_amdgcn_rcpf(s);
#pragma unroll
    for (int j = 0; j < 4; ++j) {
        x[j].x *= r; x[j].y *= r; x[j].z *= r; x[j].w *= r;
        *(float4*)(p + j * 256 + lane * 4) = x[j];
    }
}

extern "C" void kernel_launch(void* const* d_in, const int* in_sizes, int n_in,
                              void* d_out, int out_size, void* d_ws, size_t ws_size,
                              hipStream_t stream)
{
    const float* hidden = (const float*)d_in[0];  // [4,128,512]
    const float* ctx    = (const float*)d_in[1];  // [4,1024,512]
    const float* W      = (const float*)d_in[2];  // [512,512]
    const float* U      = (const float*)d_in[3];  // [512,512]
    const float* U_b    = (const float*)d_in[4];  // [512]
    const float* V      = (const float*)d_in[5];  // [512]
    float* out = (float*)d_out;                   // [4,128,1024]

    float* ewq_t = (float*)d_ws;                  // [4][512][128]  (1 MB)
    float* euc_t = ewq_t + 4 * 512 * 128;         // [4][512][1024] (8 MB)
    float* Wt    = euc_t + 4 * 512 * 1024;        // [512][512]     (1 MB)
    float* Ut    = Wt + 512 * 512;                // [512][512]     (1 MB)

    transpose512<<<dim3(8, 8, 2), 256, 0, stream>>>(W, U, Wt, Ut);
    gemm6<<<288, 256, 0, stream>>>(hidden, ctx, Wt, Ut, U_b, ewq_t, euc_t);
    fused_align5<<<dim3(8, 8, 4), 256, 0, stream>>>(ewq_t, euc_t, V, out);
    softmax_kernel<<<128, 256, 0, stream>>>(out);
}

// Round 6
// 67.920 us; speedup vs baseline: 3.9150x; 2.2575x over previous
//
#include <hip/hip_runtime.h>
#include <hip/hip_bf16.h>

// B=4, L=128, C=1024, D=512, fp32.
// out[b,l,c] = softmax_c( sum_d V[d]*tanh(wq[b,l,d] + uc[b,c,d]) )
// tanh(x) = 1 - 2/(e^{2x}+1);  e^{2(wq+uc)} = e^{2wq} * e^{2uc};
// softmax shift-invariance drops the constant sum(V):
//   align'[b,l,c] = sum_d (-2 V_d) * rcp(ewq[b,d,l]*euc[b,d,c] + 1)
//
// R6:
//  - gemm_mfma: fp32 GEMM on matrix cores via fp16 hi/lo split:
//      a*b ~= ah*bh + ah*bl + al*bh   (rel err ~2^-22, negligible)
//    3x mfma_f32_16x16x32_f16 per 32-k chunk. Split done in-kernel during
//    LDS staging. No transposes: A=W[m][k], B=X[c][k] both natural layout;
//    D (col=lane&15 -> c, row=(lane>>4)*4+reg -> m, m89-verified) writes
//    m-major e*_t directly. 576 blocks (2.25/CU), 2304 waves.
//  - fused_align6: 2c x 4l micro (LDS ~= VALU), d split in halves ->
//    512 blocks (2/CU). Partial sums: half0 -> d_out, half1 -> ws;
//    softmax2 adds them. V staged in LDS (no SMEM loads in hot loop).
// Learned rules: >=512 blocks; no s_load in hot loops; feed wide operand
// from LDS with 2-way-free padding.

#define SCALE2 2.8853900817779268f  // 2*log2(e)

typedef _Float16 f16x8 __attribute__((ext_vector_type(8)));
typedef float f32x4 __attribute__((ext_vector_type(4)));

// ---------------------------------------------------------------------------
// GEMM + exp2 via fp16-split MFMA.
// Block: 64 c-rows x 64 m. 4 waves; wave w owns m-slice w*16, all 64 c.
// K=512 in 16 chunks of 32. LDS: Xh/Xl/Wh/Wl [2][64][40] fp16 (40KB).
// blocks 0..63: wq (X=hidden, out ewq_t Mb=128); 64..575: uc (X=ctx, Mb=1024).
// ---------------------------------------------------------------------------
__global__ __launch_bounds__(256) void gemm_mfma(
    const float* __restrict__ hidden, const float* __restrict__ ctx,
    const float* __restrict__ Wmat, const float* __restrict__ Umat,
    const float* __restrict__ U_b,
    float* __restrict__ ewq_t, float* __restrict__ euc_t)
{
    __shared__ __align__(16) _Float16 Xh[2][64][40];
    __shared__ __align__(16) _Float16 Xl[2][64][40];
    __shared__ __align__(16) _Float16 Wh[2][64][40];
    __shared__ __align__(16) _Float16 Wl[2][64][40];

    const int tid  = threadIdx.x;
    const int lane = tid & 63;
    const int w    = tid >> 6;

    const float *X, *Wm, *bias;
    float* Ct;
    int m0, crow0, Mb, bshift;
    {
        int gb = blockIdx.x;
        if (gb < 64) {
            m0 = (gb & 7) * 64; crow0 = (gb >> 3) * 64;
            X = hidden; Wm = Wmat; bias = nullptr; Ct = ewq_t; Mb = 128; bshift = 7;
        } else {
            int g = gb - 64;
            m0 = (g & 7) * 64; crow0 = (g >> 3) * 64;
            X = ctx; Wm = Umat; bias = U_b; Ct = euc_t; Mb = 1024; bshift = 10;
        }
    }

    // staging map: thread -> (row 0..63, k-octet)
    const int sr = tid >> 2;
    const int sk = (tid & 3) * 8;
    const float* xsrc = X  + (size_t)(crow0 + sr) * 512 + sk;
    const float* wsrc = Wm + (size_t)(m0    + sr) * 512 + sk;

    f32x4 acc[4];
#pragma unroll
    for (int t = 0; t < 4; ++t) acc[t] = (f32x4){0.f, 0.f, 0.f, 0.f};

    float xr[8], wr[8];
    // prologue: load + convert + write chunk 0
    {
        float4 a = *(const float4*)(xsrc);
        float4 b = *(const float4*)(xsrc + 4);
        float4 c = *(const float4*)(wsrc);
        float4 d = *(const float4*)(wsrc + 4);
        xr[0]=a.x; xr[1]=a.y; xr[2]=a.z; xr[3]=a.w; xr[4]=b.x; xr[5]=b.y; xr[6]=b.z; xr[7]=b.w;
        wr[0]=c.x; wr[1]=c.y; wr[2]=c.z; wr[3]=c.w; wr[4]=d.x; wr[5]=d.y; wr[6]=d.z; wr[7]=d.w;
        f16x8 xh, xl, wh, wl;
#pragma unroll
        for (int i = 0; i < 8; ++i) {
            xh[i] = (_Float16)xr[i]; xl[i] = (_Float16)(xr[i] - (float)xh[i]);
            wh[i] = (_Float16)wr[i]; wl[i] = (_Float16)(wr[i] - (float)wh[i]);
        }
        *(f16x8*)&Xh[0][sr][sk] = xh; *(f16x8*)&Xl[0][sr][sk] = xl;
        *(f16x8*)&Wh[0][sr][sk] = wh; *(f16x8*)&Wl[0][sr][sk] = wl;
    }

    const int fr = lane & 15;          // frag row/col
    const int fk = (lane >> 4) * 8;    // frag k-offset
    const int mrow = w * 16 + fr;

    for (int kc = 0; kc < 16; ++kc) {
        if (kc < 15) {   // issue next-chunk global loads (hide under mfma)
            float4 a = *(const float4*)(xsrc + (kc + 1) * 32);
            float4 b = *(const float4*)(xsrc + (kc + 1) * 32 + 4);
            float4 c = *(const float4*)(wsrc + (kc + 1) * 32);
            float4 d = *(const float4*)(wsrc + (kc + 1) * 32 + 4);
            xr[0]=a.x; xr[1]=a.y; xr[2]=a.z; xr[3]=a.w; xr[4]=b.x; xr[5]=b.y; xr[6]=b.z; xr[7]=b.w;
            wr[0]=c.x; wr[1]=c.y; wr[2]=c.z; wr[3]=c.w; wr[4]=d.x; wr[5]=d.y; wr[6]=d.z; wr[7]=d.w;
        }
        __syncthreads();   // chunk kc writes complete
        const int bu = kc & 1;
        const f16x8 ah = *(const f16x8*)&Wh[bu][mrow][fk];
        const f16x8 al = *(const f16x8*)&Wl[bu][mrow][fk];
#pragma unroll
        for (int t = 0; t < 4; ++t) {
            const f16x8 bh = *(const f16x8*)&Xh[bu][t * 16 + fr][fk];
            const f16x8 bl = *(const f16x8*)&Xl[bu][t * 16 + fr][fk];
            acc[t] = __builtin_amdgcn_mfma_f32_16x16x32_f16(ah, bh, acc[t], 0, 0, 0);
            acc[t] = __builtin_amdgcn_mfma_f32_16x16x32_f16(ah, bl, acc[t], 0, 0, 0);
            acc[t] = __builtin_amdgcn_mfma_f32_16x16x32_f16(al, bh, acc[t], 0, 0, 0);
        }
        if (kc < 15) {   // convert + write into other buffer (no barrier needed)
            f16x8 xh, xl, wh, wl;
#pragma unroll
            for (int i = 0; i < 8; ++i) {
                xh[i] = (_Float16)xr[i]; xl[i] = (_Float16)(xr[i] - (float)xh[i]);
                wh[i] = (_Float16)wr[i]; wl[i] = (_Float16)(wr[i] - (float)wh[i]);
            }
            *(f16x8*)&Xh[bu ^ 1][sr][sk] = xh; *(f16x8*)&Xl[bu ^ 1][sr][sk] = xl;
            *(f16x8*)&Wh[bu ^ 1][sr][sk] = wh; *(f16x8*)&Wl[bu ^ 1][sr][sk] = wl;
        }
    }

    // epilogue: bias + exp2 + store. D: col=fr (c), row=(lane>>4)*4+r (m).
    const int rbase = m0 + w * 16 + (lane >> 4) * 4;
    float bl4[4] = {0.f, 0.f, 0.f, 0.f};
    if (bias) {
        float4 t = *(const float4*)&bias[rbase];
        bl4[0] = t.x; bl4[1] = t.y; bl4[2] = t.z; bl4[3] = t.w;
    }
    const int bidx = crow0 >> bshift;
    const int cl0  = crow0 & (Mb - 1);
    float* obase = Ct + ((size_t)bidx * 512 + rbase) * Mb + cl0 + fr;
#pragma unroll
    for (int r = 0; r < 4; ++r)
#pragma unroll
        for (int t = 0; t < 4; ++t)
            obase[(size_t)r * Mb + t * 16] =
                __builtin_amdgcn_exp2f(SCALE2 * (acc[t][r] + bl4[r]));
}

// ---------------------------------------------------------------------------
// Fused align, d-split. Block = (128 c, 16 l, b*2+h); 4 waves; wave w owns
// 4 l's; lane owns 2 c's (lane, lane+64; +68 pad keeps 2-way-free banks).
// Each block sums d in [h*256, h*256+256); partials: h0 -> out, h1 -> part1.
// V staged in LDS (broadcast b32 reads; no scalar loads in hot loop).
// ---------------------------------------------------------------------------
__global__ __launch_bounds__(256) void fused_align6(
    const float* __restrict__ ewq_t,  // [4][512][128]
    const float* __restrict__ euc_t,  // [4][512][1024]
    const float* __restrict__ Vv,     // [512]
    float* __restrict__ part0,        // = d_out
    float* __restrict__ part1)        // ws
{
    __shared__ float uc_s[32][132];
    __shared__ float wq_s[32][16];
    __shared__ float v_s[256];

    const int tid  = threadIdx.x;
    const int lane = tid & 63;
    const int w    = __builtin_amdgcn_readfirstlane(tid >> 6);
    const int c0   = blockIdx.x * 128;  // 8
    const int lblk = blockIdx.y * 16;   // 8
    const int zz   = blockIdx.z;        // 8
    const int b    = zz >> 1, h = zz & 1;
    const int d0   = h * 256;

    const float* ucb = euc_t + ((size_t)b * 512 + d0) * 1024 + c0;
    const float* wqb = ewq_t + ((size_t)b * 512 + d0) * 128 + lblk;

    v_s[tid] = Vv[d0 + tid];

    // staging maps
    const int ud = tid >> 3;            // 0..31 d
    const int uq = tid & 7;             // col groups 4*(uq+8i)
    const int wd = tid >> 2, wl = (tid & 3) * 4;   // tid<128 only

    float4 ur[4];
    float4 qr;
    {
        const float* src = ucb + (size_t)ud * 1024;
#pragma unroll
        for (int i = 0; i < 4; ++i)
            ur[i] = *(const float4*)(src + (uq + 8 * i) * 4);
        if (tid < 128)
            qr = *(const float4*)(wqb + (size_t)wd * 128 + wl);
    }

    float a00 = 0.f, a01 = 0.f, a10 = 0.f, a11 = 0.f;
    float a20 = 0.f, a21 = 0.f, a30 = 0.f, a31 = 0.f;

    for (int dc = 0; dc < 8; ++dc) {
        __syncthreads();   // previous compute done before overwrite
#pragma unroll
        for (int i = 0; i < 4; ++i) {
            const int c  = (uq + 8 * i) * 4;
            const int cs = c + ((c >> 6) << 2);   // +4 pad for c>=64
            *(float4*)&uc_s[ud][cs] = ur[i];
        }
        if (tid < 128) *(float4*)&wq_s[wd][wl] = qr;
        __syncthreads();

        if (dc < 7) {   // prefetch next chunk
            const float* src = ucb + (size_t)((dc + 1) * 32 + ud) * 1024;
#pragma unroll
            for (int i = 0; i < 4; ++i)
                ur[i] = *(const float4*)(src + (uq + 8 * i) * 4);
            if (tid < 128)
                qr = *(const float4*)(wqb + (size_t)((dc + 1) * 32 + wd) * 128 + wl);
        }

        const int vb = dc * 32;
#pragma unroll 8
        for (int d = 0; d < 32; ++d) {
            const float  e0 = uc_s[d][lane];
            const float  e1 = uc_s[d][lane + 68];
            const float4 q  = *(const float4*)&wq_s[d][w * 4];
            const float  vv = v_s[vb + d];
            a00 = fmaf(vv, __builtin_amdgcn_rcpf(fmaf(q.x, e0, 1.0f)), a00);
            a01 = fmaf(vv, __builtin_amdgcn_rcpf(fmaf(q.x, e1, 1.0f)), a01);
            a10 = fmaf(vv, __builtin_amdgcn_rcpf(fmaf(q.y, e0, 1.0f)), a10);
            a11 = fmaf(vv, __builtin_amdgcn_rcpf(fmaf(q.y, e1, 1.0f)), a11);
            a20 = fmaf(vv, __builtin_amdgcn_rcpf(fmaf(q.z, e0, 1.0f)), a20);
            a21 = fmaf(vv, __builtin_amdgcn_rcpf(fmaf(q.z, e1, 1.0f)), a21);
            a30 = fmaf(vv, __builtin_amdgcn_rcpf(fmaf(q.w, e0, 1.0f)), a30);
            a31 = fmaf(vv, __builtin_amdgcn_rcpf(fmaf(q.w, e1, 1.0f)), a31);
        }
    }

    float* op = (h ? part1 : part0) + ((size_t)b * 128 + lblk + w * 4) * 1024 + c0 + lane;
    op[0]         = -2.0f * a00;  op[64]        = -2.0f * a01;
    op[1024]      = -2.0f * a10;  op[1024 + 64] = -2.0f * a11;
    op[2048]      = -2.0f * a20;  op[2048 + 64] = -2.0f * a21;
    op[3072]      = -2.0f * a30;  op[3072 + 64] = -2.0f * a31;
}

// in-place softmax over rows of 1024 of (data + part1); one wave per row
__global__ __launch_bounds__(256) void softmax2(
    float* __restrict__ data, const float* __restrict__ part1)
{
    const int row  = blockIdx.x * 4 + (threadIdx.x >> 6);
    const int lane = threadIdx.x & 63;
    float* p = data + (size_t)row * 1024;
    const float* q = part1 + (size_t)row * 1024;

    float4 x[4];
#pragma unroll
    for (int j = 0; j < 4; ++j) {
        float4 a = *(const float4*)(p + j * 256 + lane * 4);
        float4 b = *(const float4*)(q + j * 256 + lane * 4);
        x[j].x = a.x + b.x; x[j].y = a.y + b.y;
        x[j].z = a.z + b.z; x[j].w = a.w + b.w;
    }

    float m = x[0].x;
#pragma unroll
    for (int j = 0; j < 4; ++j) {
        m = fmaxf(m, x[j].x); m = fmaxf(m, x[j].y);
        m = fmaxf(m, x[j].z); m = fmaxf(m, x[j].w);
    }
#pragma unroll
    for (int mask = 32; mask >= 1; mask >>= 1) m = fmaxf(m, __shfl_xor(m, mask, 64));

    const float LOG2E = 1.4426950408889634f;
    float s = 0.0f;
#pragma unroll
    for (int j = 0; j < 4; ++j) {
        x[j].x = __builtin_amdgcn_exp2f((x[j].x - m) * LOG2E);
        x[j].y = __builtin_amdgcn_exp2f((x[j].y - m) * LOG2E);
        x[j].z = __builtin_amdgcn_exp2f((x[j].z - m) * LOG2E);
        x[j].w = __builtin_amdgcn_exp2f((x[j].w - m) * LOG2E);
        s += x[j].x + x[j].y + x[j].z + x[j].w;
    }
#pragma unroll
    for (int mask = 32; mask >= 1; mask >>= 1) s += __shfl_xor(s, mask, 64);
    const float r = __builtin_amdgcn_rcpf(s);
#pragma unroll
    for (int j = 0; j < 4; ++j) {
        x[j].x *= r; x[j].y *= r; x[j].z *= r; x[j].w *= r;
        *(float4*)(p + j * 256 + lane * 4) = x[j];
    }
}

extern "C" void kernel_launch(void* const* d_in, const int* in_sizes, int n_in,
                              void* d_out, int out_size, void* d_ws, size_t ws_size,
                              hipStream_t stream)
{
    const float* hidden = (const float*)d_in[0];  // [4,128,512]
    const float* ctx    = (const float*)d_in[1];  // [4,1024,512]
    const float* W      = (const float*)d_in[2];  // [512,512]
    const float* U      = (const float*)d_in[3];  // [512,512]
    const float* U_b    = (const float*)d_in[4];  // [512]
    const float* V      = (const float*)d_in[5];  // [512]
    float* out = (float*)d_out;                   // [4,128,1024]

    float* ewq_t = (float*)d_ws;                  // [4][512][128]   (1 MB)
    float* euc_t = ewq_t + 4 * 512 * 128;         // [4][512][1024]  (8 MB)
    float* part1 = euc_t + 4 * 512 * 1024;        // [4][128][1024]  (2 MB)

    gemm_mfma<<<576, 256, 0, stream>>>(hidden, ctx, W, U, U_b, ewq_t, euc_t);
    fused_align6<<<dim3(8, 8, 8), 256, 0, stream>>>(ewq_t, euc_t, V, out, part1);
    softmax2<<<128, 256, 0, stream>>>(out, part1);
}

// Round 7
// 59.413 us; speedup vs baseline: 4.4756x; 1.1432x over previous
//
#include <hip/hip_runtime.h>
#include <hip/hip_bf16.h>

// B=4, L=128, C=1024, D=512, fp32.
// out[b,l,c] = softmax_c( sum_d V[d]*tanh(wq[b,l,d] + uc[b,c,d]) )
// tanh(x) = 1 - 2/(e^{2x}+1);  e^{2(wq+uc)} = e^{2wq} * e^{2uc};
// softmax shift-invariance drops the constant sum(V):
//   align'[b,l,c] = sum_d (-2 V_d) * rcp(ewq[b,d,l]*euc[b,d,c] + 1)
//
// R7:
//  - gemm_mfma unchanged (fp16 hi/lo split MFMA, ~16us).
//  - fused_align7: LDS slot-count optimization. Lane owns 4 CONSECUTIVE c
//    (one conflict-free b128 e-read), wave owns 4 l (one uniform b128 q-read)
//    -> 29.8 LDS-cyc per 1024 elems ~= trans floor. Staging via
//    global_load_lds width16 (no ds_write slots, no staging VGPRs).
//    d-split 4 -> 512 blocks (2/CU); partials out,p1,p2,p3; softmax3 sums.

#define SCALE2 2.8853900817779268f  // 2*log2(e)

typedef _Float16 f16x8 __attribute__((ext_vector_type(8)));
typedef float f32x4 __attribute__((ext_vector_type(4)));

__device__ __forceinline__ void gload16(const void* g, void* l) {
    __builtin_amdgcn_global_load_lds(
        (const __attribute__((address_space(1))) void*)g,
        (__attribute__((address_space(3))) void*)l,
        16, 0, 0);
}

// ---------------------------------------------------------------------------
// GEMM + exp2 via fp16-split MFMA (unchanged from R6).
// ---------------------------------------------------------------------------
__global__ __launch_bounds__(256) void gemm_mfma(
    const float* __restrict__ hidden, const float* __restrict__ ctx,
    const float* __restrict__ Wmat, const float* __restrict__ Umat,
    const float* __restrict__ U_b,
    float* __restrict__ ewq_t, float* __restrict__ euc_t)
{
    __shared__ __align__(16) _Float16 Xh[2][64][40];
    __shared__ __align__(16) _Float16 Xl[2][64][40];
    __shared__ __align__(16) _Float16 Wh[2][64][40];
    __shared__ __align__(16) _Float16 Wl[2][64][40];

    const int tid  = threadIdx.x;
    const int lane = tid & 63;
    const int w    = tid >> 6;

    const float *X, *Wm, *bias;
    float* Ct;
    int m0, crow0, Mb, bshift;
    {
        int gb = blockIdx.x;
        if (gb < 64) {
            m0 = (gb & 7) * 64; crow0 = (gb >> 3) * 64;
            X = hidden; Wm = Wmat; bias = nullptr; Ct = ewq_t; Mb = 128; bshift = 7;
        } else {
            int g = gb - 64;
            m0 = (g & 7) * 64; crow0 = (g >> 3) * 64;
            X = ctx; Wm = Umat; bias = U_b; Ct = euc_t; Mb = 1024; bshift = 10;
        }
    }

    const int sr = tid >> 2;
    const int sk = (tid & 3) * 8;
    const float* xsrc = X  + (size_t)(crow0 + sr) * 512 + sk;
    const float* wsrc = Wm + (size_t)(m0    + sr) * 512 + sk;

    f32x4 acc[4];
#pragma unroll
    for (int t = 0; t < 4; ++t) acc[t] = (f32x4){0.f, 0.f, 0.f, 0.f};

    float xr[8], wr[8];
    {
        float4 a = *(const float4*)(xsrc);
        float4 b = *(const float4*)(xsrc + 4);
        float4 c = *(const float4*)(wsrc);
        float4 d = *(const float4*)(wsrc + 4);
        xr[0]=a.x; xr[1]=a.y; xr[2]=a.z; xr[3]=a.w; xr[4]=b.x; xr[5]=b.y; xr[6]=b.z; xr[7]=b.w;
        wr[0]=c.x; wr[1]=c.y; wr[2]=c.z; wr[3]=c.w; wr[4]=d.x; wr[5]=d.y; wr[6]=d.z; wr[7]=d.w;
        f16x8 xh, xl, wh, wl;
#pragma unroll
        for (int i = 0; i < 8; ++i) {
            xh[i] = (_Float16)xr[i]; xl[i] = (_Float16)(xr[i] - (float)xh[i]);
            wh[i] = (_Float16)wr[i]; wl[i] = (_Float16)(wr[i] - (float)wh[i]);
        }
        *(f16x8*)&Xh[0][sr][sk] = xh; *(f16x8*)&Xl[0][sr][sk] = xl;
        *(f16x8*)&Wh[0][sr][sk] = wh; *(f16x8*)&Wl[0][sr][sk] = wl;
    }

    const int fr = lane & 15;
    const int fk = (lane >> 4) * 8;
    const int mrow = w * 16 + fr;

    for (int kc = 0; kc < 16; ++kc) {
        if (kc < 15) {
            float4 a = *(const float4*)(xsrc + (kc + 1) * 32);
            float4 b = *(const float4*)(xsrc + (kc + 1) * 32 + 4);
            float4 c = *(const float4*)(wsrc + (kc + 1) * 32);
            float4 d = *(const float4*)(wsrc + (kc + 1) * 32 + 4);
            xr[0]=a.x; xr[1]=a.y; xr[2]=a.z; xr[3]=a.w; xr[4]=b.x; xr[5]=b.y; xr[6]=b.z; xr[7]=b.w;
            wr[0]=c.x; wr[1]=c.y; wr[2]=c.z; wr[3]=c.w; wr[4]=d.x; wr[5]=d.y; wr[6]=d.z; wr[7]=d.w;
        }
        __syncthreads();
        const int bu = kc & 1;
        const f16x8 ah = *(const f16x8*)&Wh[bu][mrow][fk];
        const f16x8 al = *(const f16x8*)&Wl[bu][mrow][fk];
#pragma unroll
        for (int t = 0; t < 4; ++t) {
            const f16x8 bh = *(const f16x8*)&Xh[bu][t * 16 + fr][fk];
            const f16x8 bl = *(const f16x8*)&Xl[bu][t * 16 + fr][fk];
            acc[t] = __builtin_amdgcn_mfma_f32_16x16x32_f16(ah, bh, acc[t], 0, 0, 0);
            acc[t] = __builtin_amdgcn_mfma_f32_16x16x32_f16(ah, bl, acc[t], 0, 0, 0);
            acc[t] = __builtin_amdgcn_mfma_f32_16x16x32_f16(al, bh, acc[t], 0, 0, 0);
        }
        if (kc < 15) {
            f16x8 xh, xl, wh, wl;
#pragma unroll
            for (int i = 0; i < 8; ++i) {
                xh[i] = (_Float16)xr[i]; xl[i] = (_Float16)(xr[i] - (float)xh[i]);
                wh[i] = (_Float16)wr[i]; wl[i] = (_Float16)(wr[i] - (float)wh[i]);
            }
            *(f16x8*)&Xh[bu ^ 1][sr][sk] = xh; *(f16x8*)&Xl[bu ^ 1][sr][sk] = xl;
            *(f16x8*)&Wh[bu ^ 1][sr][sk] = wh; *(f16x8*)&Wl[bu ^ 1][sr][sk] = wl;
        }
    }

    const int rbase = m0 + w * 16 + (lane >> 4) * 4;
    float bl4[4] = {0.f, 0.f, 0.f, 0.f};
    if (bias) {
        float4 t = *(const float4*)&bias[rbase];
        bl4[0] = t.x; bl4[1] = t.y; bl4[2] = t.z; bl4[3] = t.w;
    }
    const int bidx = crow0 >> bshift;
    const int cl0  = crow0 & (Mb - 1);
    float* obase = Ct + ((size_t)bidx * 512 + rbase) * Mb + cl0 + fr;
#pragma unroll
    for (int r = 0; r < 4; ++r)
#pragma unroll
        for (int t = 0; t < 4; ++t)
            obase[(size_t)r * Mb + t * 16] =
                __builtin_amdgcn_exp2f(SCALE2 * (acc[t][r] + bl4[r]));
}

// ---------------------------------------------------------------------------
// Fused align v7. Block = 256 c x 16 l x 128 d. 4 waves; wave w owns l-group
// w (4 l's), lane owns 4 consecutive c (c0 + 4*lane .. +3).
// Per d: 1 ds_read_b128 (e, conflict-free contiguous), 1 uniform b128 (q),
// 1 b32 broadcast (v) -> 16 rcp+32 fma. Staging: global_load_lds w16,
// double-buffered, one __syncthreads per 32-d chunk.
// Grid (4, 8, 16): z = b*4 + h; partial h -> p[h]; softmax3 sums.
// ---------------------------------------------------------------------------
__global__ __launch_bounds__(256) void fused_align7(
    const float* __restrict__ ewq_t,  // [4][512][128]
    const float* __restrict__ euc_t,  // [4][512][1024]
    const float* __restrict__ Vv,     // [512]
    float* __restrict__ p0, float* __restrict__ p1,
    float* __restrict__ p2, float* __restrict__ p3)
{
    __shared__ __align__(16) float uc_s[2][32][256];  // 64 KB
    __shared__ __align__(16) float wq_s[2][32][16];   // 4 KB
    __shared__ float v_s[128];

    const int tid  = threadIdx.x;
    const int lane = tid & 63;
    const int w    = __builtin_amdgcn_readfirstlane(tid >> 6);
    const int c0   = blockIdx.x * 256;   // 4
    const int l0   = blockIdx.y * 16;    // 8
    const int z    = blockIdx.z;         // 16
    const int b    = z >> 2, h = z & 3;
    const int d0   = h * 128;

    const float* ucb = euc_t + ((size_t)b * 512 + d0) * 1024 + c0;
    const float* wqb = ewq_t + ((size_t)b * 512 + d0) * 128 + l0;

    if (tid < 128) v_s[tid] = Vv[d0 + tid];

    // stage chunk (32 d) into buf: uc rows via gload16 (wave w: rows w*8..+7),
    // wq rows via gload16 (waves 0,1: 16 rows each).
#define STAGE(buf, chunk)                                                     \
    {                                                                         \
        const float* src_ = ucb + (size_t)((chunk) * 32) * 1024;              \
        _Pragma("unroll")                                                     \
        for (int i_ = 0; i_ < 8; ++i_) {                                      \
            const int d_ = w * 8 + i_;                                        \
            gload16(src_ + (size_t)d_ * 1024 + lane * 4, &uc_s[buf][d_][0]);  \
        }                                                                     \
        if (w < 2) {                                                          \
            const float* ws_ = wqb + (size_t)((chunk) * 32 + w * 16) * 128;   \
            gload16(ws_ + (size_t)(lane >> 2) * 128 + (lane & 3) * 4,         \
                    &wq_s[buf][w * 16][0]);                                   \
        }                                                                     \
    }

    float4 acc[4];
#pragma unroll
    for (int i = 0; i < 4; ++i) acc[i] = make_float4(0.f, 0.f, 0.f, 0.f);

    STAGE(0, 0);
    __syncthreads();

    for (int k = 0; k < 4; ++k) {
        if (k < 3) STAGE((k + 1) & 1, k + 1);
        const int bu = k & 1;
#pragma unroll 4
        for (int d = 0; d < 32; ++d) {
            const float4 e = *(const float4*)&uc_s[bu][d][lane * 4];
            const float4 q = *(const float4*)&wq_s[bu][d][w * 4];
            const float vv = v_s[k * 32 + d];
            const float qc[4] = {q.x, q.y, q.z, q.w};
#pragma unroll
            for (int i = 0; i < 4; ++i) {
                acc[i].x = fmaf(vv, __builtin_amdgcn_rcpf(fmaf(qc[i], e.x, 1.0f)), acc[i].x);
                acc[i].y = fmaf(vv, __builtin_amdgcn_rcpf(fmaf(qc[i], e.y, 1.0f)), acc[i].y);
                acc[i].z = fmaf(vv, __builtin_amdgcn_rcpf(fmaf(qc[i], e.z, 1.0f)), acc[i].z);
                acc[i].w = fmaf(vv, __builtin_amdgcn_rcpf(fmaf(qc[i], e.w, 1.0f)), acc[i].w);
            }
        }
        __syncthreads();   // drains gload_lds (vmcnt) + protects buf reuse
    }
#undef STAGE

    float* pp = (h == 0) ? p0 : (h == 1) ? p1 : (h == 2) ? p2 : p3;
#pragma unroll
    for (int i = 0; i < 4; ++i) {
        float4 r;
        r.x = -2.0f * acc[i].x; r.y = -2.0f * acc[i].y;
        r.z = -2.0f * acc[i].z; r.w = -2.0f * acc[i].w;
        *(float4*)(pp + ((size_t)b * 128 + l0 + w * 4 + i) * 1024 + c0 + lane * 4) = r;
    }
}

// in-place softmax over rows of 1024 of (p0+p1+p2+p3); one wave per row
__global__ __launch_bounds__(256) void softmax3(
    float* __restrict__ data, const float* __restrict__ p1,
    const float* __restrict__ p2, const float* __restrict__ p3)
{
    const int row  = blockIdx.x * 4 + (threadIdx.x >> 6);
    const int lane = threadIdx.x & 63;
    float* p = data + (size_t)row * 1024;
    const float* q1 = p1 + (size_t)row * 1024;
    const float* q2 = p2 + (size_t)row * 1024;
    const float* q3 = p3 + (size_t)row * 1024;

    float4 x[4];
#pragma unroll
    for (int j = 0; j < 4; ++j) {
        float4 a = *(const float4*)(p  + j * 256 + lane * 4);
        float4 b = *(const float4*)(q1 + j * 256 + lane * 4);
        float4 c = *(const float4*)(q2 + j * 256 + lane * 4);
        float4 d = *(const float4*)(q3 + j * 256 + lane * 4);
        x[j].x = (a.x + b.x) + (c.x + d.x);
        x[j].y = (a.y + b.y) + (c.y + d.y);
        x[j].z = (a.z + b.z) + (c.z + d.z);
        x[j].w = (a.w + b.w) + (c.w + d.w);
    }

    float m = x[0].x;
#pragma unroll
    for (int j = 0; j < 4; ++j) {
        m = fmaxf(m, x[j].x); m = fmaxf(m, x[j].y);
        m = fmaxf(m, x[j].z); m = fmaxf(m, x[j].w);
    }
#pragma unroll
    for (int mask = 32; mask >= 1; mask >>= 1) m = fmaxf(m, __shfl_xor(m, mask, 64));

    const float LOG2E = 1.4426950408889634f;
    float s = 0.0f;
#pragma unroll
    for (int j = 0; j < 4; ++j) {
        x[j].x = __builtin_amdgcn_exp2f((x[j].x - m) * LOG2E);
        x[j].y = __builtin_amdgcn_exp2f((x[j].y - m) * LOG2E);
        x[j].z = __builtin_amdgcn_exp2f((x[j].z - m) * LOG2E);
        x[j].w = __builtin_amdgcn_exp2f((x[j].w - m) * LOG2E);
        s += x[j].x + x[j].y + x[j].z + x[j].w;
    }
#pragma unroll
    for (int mask = 32; mask >= 1; mask >>= 1) s += __shfl_xor(s, mask, 64);
    const float r = __builtin_amdgcn_rcpf(s);
#pragma unroll
    for (int j = 0; j < 4; ++j) {
        x[j].x *= r; x[j].y *= r; x[j].z *= r; x[j].w *= r;
        *(float4*)(p + j * 256 + lane * 4) = x[j];
    }
}

extern "C" void kernel_launch(void* const* d_in, const int* in_sizes, int n_in,
                              void* d_out, int out_size, void* d_ws, size_t ws_size,
                              hipStream_t stream)
{
    const float* hidden = (const float*)d_in[0];  // [4,128,512]
    const float* ctx    = (const float*)d_in[1];  // [4,1024,512]
    const float* W      = (const float*)d_in[2];  // [512,512]
    const float* U      = (const float*)d_in[3];  // [512,512]
    const float* U_b    = (const float*)d_in[4];  // [512]
    const float* V      = (const float*)d_in[5];  // [512]
    float* out = (float*)d_out;                   // [4,128,1024]

    float* ewq_t = (float*)d_ws;                  // [4][512][128]   (1 MB)
    float* euc_t = ewq_t + 4 * 512 * 128;         // [4][512][1024]  (8 MB)
    float* p1    = euc_t + 4 * 512 * 1024;        // [4][128][1024]  (2 MB)
    float* p2    = p1 + 4 * 128 * 1024;           // (2 MB)
    float* p3    = p2 + 4 * 128 * 1024;           // (2 MB)

    gemm_mfma<<<576, 256, 0, stream>>>(hidden, ctx, W, U, U_b, ewq_t, euc_t);
    fused_align7<<<dim3(4, 8, 16), 256, 0, stream>>>(ewq_t, euc_t, V, out, p1, p2, p3);
    softmax3<<<128, 256, 0, stream>>>(out, p1, p2, p3);
}